// Round 2
// baseline (690.285 us; speedup 1.0000x reference)
//
#include <hip/hip_runtime.h>
#include <hip/hip_bf16.h>
#include <math.h>

// Problem dims (fixed by setup_inputs)
#define B_  8
#define CM  80
#define T1_ 800
#define CT  512
#define T2_ 200
#define CA  80

using bf16 = __hip_bfloat16;

// Runtime-dtype float load: isf32 selects fp32 vs bf16 interpretation.
__device__ __forceinline__ float load_sel(const void* p, long idx, int isf32) {
  if (isf32) return ((const float*)p)[idx];
  return __bfloat162float(((const bf16*)p)[idx]);
}

// ---------------------------------------------------------------------------
// Detection + mask normalization (single block).
// flags[0] = 1 if float tensors are fp32, 0 if bf16.
// mf[i] = 0/1 mask as float, decoded from uint8 / int32 / fp32 / bf16 storage.
// ---------------------------------------------------------------------------
__global__ void k_detect(const unsigned short* __restrict__ q,
                         const void* __restrict__ mraw, int nmask,
                         float* __restrict__ mf, int* __restrict__ flags) {
  __shared__ int s_insane;
  __shared__ int s_fmt;  // 3=uint8, 2=bf16, 1=4-byte words (int32/fp32)
  const int tid = threadIdx.x;
  if (tid == 0) { s_insane = 0; s_fmt = 1; }
  __syncthreads();

  // --- float dtype probe on queries (even-indexed bf16 halves) ---
  if (tid < 128) {
    unsigned short u = q[2 * tid];
    int e = (u >> 7) & 0xFF;
    if (e < 100 || e > 154) atomicAdd(&s_insane, 1);
  }

  // --- mask format probe: scan nmask BYTES (safe under all hypotheses) ---
  const unsigned int* wi = (const unsigned int*)mraw;
  const int nw = nmask / 4;
  int pri = 0;
  for (int i = tid; i < nw; i += 256) {
    unsigned int w = wi[i];
    if (w == 0u || w == 1u) continue;            // int32-compatible
    if (w == 0x3F803F80u || w == 0x00003F80u) { pri = max(pri, 2); continue; }
    if (w == 0x3F800000u) continue;              // fp32 1.0f (4-byte decode ok)
    unsigned int b0 = w & 0xFFu, b1 = (w >> 8) & 0xFFu,
                 b2 = (w >> 16) & 0xFFu, b3 = (w >> 24) & 0xFFu;
    if (b0 <= 1u && b1 <= 1u && b2 <= 1u && b3 <= 1u) pri = max(pri, 3);
    else pri = max(pri, 2);                      // odd pattern -> bf16 halves
  }
  if (pri) atomicMax(&s_fmt, pri);
  __syncthreads();

  const int fmt = s_fmt;
  for (int i = tid; i < nmask; i += 256) {
    int m;
    if (fmt == 3)      m = ((const unsigned char*)mraw)[i] != 0;
    else if (fmt == 2) m = ((const unsigned short*)mraw)[i] != 0;
    else               m = (wi[i] != 0u);
    mf[i] = (float)m;
  }
  if (tid == 0) flags[0] = (s_insane >= 32) ? 1 : 0;
}

// ---------------------------------------------------------------------------
// Generic conv1d (stride 1) as tiled GEMM, per batch:
//   Y[b][co][t] = bias[co] + sum_{ci,dk} W[co][ci][dk] * X[b][ci][t+dk-pad]
// 64x64 output tile, BK=16, fp32 accumulate in ws, optional ReLU.
// X dtype: xraw ? (per flags[0]) : fp32 workspace. W/bias: per flags[0].
// ---------------------------------------------------------------------------
__global__ __launch_bounds__(256) void k_conv(
    const void* __restrict__ X, const void* __restrict__ W,
    const void* __restrict__ bias, float* __restrict__ Y,
    const int* __restrict__ flags, int xraw,
    int Cin, int Cout, int T, int KW, int pad, int relu) {
  const int inf = flags[0];          // 1 = fp32 inputs
  const int xf = xraw ? inf : 1;
  const int K  = Cin * KW;
  const int b  = blockIdx.z;
  const int m0 = blockIdx.y * 64;
  const int n0 = blockIdx.x * 64;
  const int tid = threadIdx.x;
  const int tx = tid & 15;   // n direction
  const int ty = tid >> 4;   // m direction

  __shared__ float As[16][64];   // [k][m]
  __shared__ float Bs[16][65];   // [k][n], +1 pad

  float acc[4][4] = {{0.f}};
  const long xbase = (long)b * Cin * T;

  for (int k0 = 0; k0 < K; k0 += 16) {
    for (int i = tid; i < 64 * 16; i += 256) {
      int m = i >> 4, k = i & 15;
      int gm = m0 + m;
      float v = 0.f;
      if (gm < Cout) v = load_sel(W, (long)gm * K + (k0 + k), inf);
      As[k][m] = v;
    }
    for (int i = tid; i < 16 * 64; i += 256) {
      int k = i >> 6, n = i & 63;
      int gk = k0 + k;
      int ci = gk / KW;
      int dk = gk - ci * KW;
      int t = n0 + n + dk - pad;
      float v = 0.f;
      if (t >= 0 && t < T) v = load_sel(X, xbase + (long)ci * T + t, xf);
      Bs[k][n] = v;
    }
    __syncthreads();
#pragma unroll
    for (int kk = 0; kk < 16; ++kk) {
      float a[4], bv[4];
#pragma unroll
      for (int i = 0; i < 4; ++i) a[i] = As[kk][ty * 4 + i];
#pragma unroll
      for (int j = 0; j < 4; ++j) bv[j] = Bs[kk][tx * 4 + j];
#pragma unroll
      for (int i = 0; i < 4; ++i)
#pragma unroll
        for (int j = 0; j < 4; ++j)
          acc[i][j] = fmaf(a[i], bv[j], acc[i][j]);
    }
    __syncthreads();
  }

#pragma unroll
  for (int i = 0; i < 4; ++i) {
    int gm = m0 + ty * 4 + i;
    if (gm >= Cout) continue;
    float bi = load_sel(bias, gm, inf);
#pragma unroll
    for (int j = 0; j < 4; ++j) {
      int gn = n0 + tx * 4 + j;
      if (gn >= T) continue;
      float v = acc[i][j] + bi;
      if (relu) v = fmaxf(v, 0.f);
      Y[((long)b * Cout + gm) * T + gn] = v;
    }
  }
}

// ---------------------------------------------------------------------------
// Distance + log_softmax + prior + masked softmax. One block per (b, t1).
// ---------------------------------------------------------------------------
__global__ __launch_bounds__(256) void k_dist(
    const float* __restrict__ qe, const float* __restrict__ ke,
    const void* __restrict__ prior, const float* __restrict__ mf,
    void* __restrict__ out, const int* __restrict__ flags) {
  const int f   = flags[0];
  const int t1  = blockIdx.x;
  const int b   = blockIdx.y;
  const int tid = threadIdx.x;

  __shared__ float qv[CA];
  __shared__ float red[8];

  if (tid < CA) qv[tid] = qe[((long)b * CA + tid) * T1_ + t1];
  __syncthreads();

  const int t2 = tid;
  const bool valid = (t2 < T2_);
  float x = -INFINITY;
  if (valid) {
    const float* kb = ke + (long)b * CA * T2_ + t2;
    float s = 0.f;
#pragma unroll 8
    for (int c = 0; c < CA; ++c) {
      float d = qv[c] - kb[c * T2_];
      s = fmaf(d, d, s);
    }
    x = -0.0005f * s;
  }

  // --- max over row ---
  float m = x;
#pragma unroll
  for (int o = 32; o > 0; o >>= 1) m = fmaxf(m, __shfl_down(m, o, 64));
  if ((tid & 63) == 0) red[tid >> 6] = m;
  __syncthreads();
  const float M1 = fmaxf(fmaxf(red[0], red[1]), fmaxf(red[2], red[3]));

  // --- sum exp ---
  float e = (x == -INFINITY) ? 0.f : expf(x - M1);
  float ssum = e;
#pragma unroll
  for (int o = 32; o > 0; o >>= 1) ssum += __shfl_down(ssum, o, 64);
  if ((tid & 63) == 0) red[(tid >> 6) + 4] = ssum;
  __syncthreads();
  const float S1 = red[4] + red[5] + red[6] + red[7];
  const float logZ = logf(S1);

  const long oidx = ((long)b * T1_ + t1) * T2_ + t2;
  const long N = (long)B_ * T1_ * T2_;
  float lp = -INFINITY;
  if (valid) {
    float pr = load_sel(prior, oidx, f);
    lp = (x - M1 - logZ) + logf(fmaxf(pr, 0.f) + 1e-8f);
    if (f) ((float*)out)[N + oidx] = lp;
    else   ((bf16*)out)[N + oidx] = __float2bfloat16(lp);
  }

  float xm = lp;
  if (valid && mf[b * T2_ + t2] != 0.f) xm = -INFINITY;

  __syncthreads();  // red[0..3] about to be rewritten
  float m2 = xm;
#pragma unroll
  for (int o = 32; o > 0; o >>= 1) m2 = fmaxf(m2, __shfl_down(m2, o, 64));
  if ((tid & 63) == 0) red[tid >> 6] = m2;
  __syncthreads();
  const float M2 = fmaxf(fmaxf(red[0], red[1]), fmaxf(red[2], red[3]));

  float e2 = (xm == -INFINITY) ? 0.f : expf(xm - M2);
  float s2 = e2;
#pragma unroll
  for (int o = 32; o > 0; o >>= 1) s2 += __shfl_down(s2, o, 64);
  if ((tid & 63) == 0) red[(tid >> 6) + 4] = s2;
  __syncthreads();
  const float S2 = red[4] + red[5] + red[6] + red[7];

  if (valid) {
    float a = (S2 > 0.f) ? (e2 / S2) : 0.f;
    if (f) ((float*)out)[oidx] = a;
    else   ((bf16*)out)[oidx] = __float2bfloat16(a);
  }
}

// ---------------------------------------------------------------------------
extern "C" void kernel_launch(void* const* d_in, const int* in_sizes, int n_in,
                              void* d_out, int out_size, void* d_ws, size_t ws_size,
                              hipStream_t stream) {
  const void* queries = d_in[0];
  const void* keys    = d_in[1];
  // d_in[2] = query_lens (unused by reference math)
  const void* mask    = d_in[3];
  const void* prior   = d_in[4];
  const void* kp_w1 = d_in[5];
  const void* kp_b1 = d_in[6];
  const void* kp_w2 = d_in[7];
  const void* kp_b2 = d_in[8];
  const void* qp_w1 = d_in[9];
  const void* qp_b1 = d_in[10];
  const void* qp_w2 = d_in[11];
  const void* qp_b2 = d_in[12];
  const void* qp_w3 = d_in[13];
  const void* qp_b3 = d_in[14];

  // Workspace layout (fp32)
  float* ws  = (float*)d_ws;
  float* ke1 = ws;                                  // 8*1024*200 = 1,638,400
  float* ke  = ke1 + (long)B_ * 1024 * T2_;         //   128,000
  float* qe1 = ke  + (long)B_ * CA   * T2_;         // 1,024,000
  float* qe2 = qe1 + (long)B_ * 160  * T1_;         //   512,000
  float* qe  = qe2 + (long)B_ * CM   * T1_;         //   512,000
  float* mf  = qe  + (long)B_ * CA   * T1_;         //     1,600
  int* flags = (int*)(mf + B_ * T2_);

  k_detect<<<1, 256, 0, stream>>>((const unsigned short*)queries, mask,
                                  B_ * T2_, mf, flags);

  // key_proj: Conv1d(512->1024, k3, pad1) + ReLU ; Conv1d(1024->80, k1)
  k_conv<<<dim3(4, 16, B_), 256, 0, stream>>>(
      keys, kp_w1, kp_b1, ke1, flags, 1, CT, 1024, T2_, 3, 1, 1);
  k_conv<<<dim3(4, 2, B_), 256, 0, stream>>>(
      ke1, kp_w2, kp_b2, ke, flags, 0, 1024, CA, T2_, 1, 0, 0);

  // query_proj: Conv1d(80->160,k3,pad1)+ReLU; Conv1d(160->80,k1)+ReLU; Conv1d(80->80,k1)
  k_conv<<<dim3(13, 3, B_), 256, 0, stream>>>(
      queries, qp_w1, qp_b1, qe1, flags, 1, CM, 160, T1_, 3, 1, 1);
  k_conv<<<dim3(13, 2, B_), 256, 0, stream>>>(
      qe1, qp_w2, qp_b2, qe2, flags, 0, 160, CM, T1_, 1, 0, 1);
  k_conv<<<dim3(13, 2, B_), 256, 0, stream>>>(
      qe2, qp_w3, qp_b3, qe, flags, 0, CM, CA, T1_, 1, 0, 0);

  k_dist<<<dim3(T1_, B_), 256, 0, stream>>>(qe, ke, prior, mf, d_out, flags);
}

// Round 6
// 467.104 us; speedup vs baseline: 1.4778x; 1.4778x over previous
//
#include <hip/hip_runtime.h>
#include <hip/hip_bf16.h>
#include <math.h>

// Problem dims (fixed by setup_inputs)
#define B_  8
#define CM  80
#define T1_ 800
#define CT  512
#define T2_ 200
#define CA  80

using bf16 = __hip_bfloat16;

// Runtime-dtype float load: isf32 selects fp32 vs bf16 interpretation.
__device__ __forceinline__ float load_sel(const void* p, long idx, int isf32) {
  if (isf32) return ((const float*)p)[idx];
  return __bfloat162float(((const bf16*)p)[idx]);
}

// ---------------------------------------------------------------------------
// Detection + mask normalization (single block). R2-exact (proven passing).
// flags[0] = 1 if float tensors are fp32, 0 if bf16.
// mf[i] = 0/1 mask as float, decoded from uint8 / int32 / fp32 / bf16 storage.
// ---------------------------------------------------------------------------
__global__ void k_detect(const unsigned short* __restrict__ q,
                         const void* __restrict__ mraw, int nmask,
                         float* __restrict__ mf, int* __restrict__ flags) {
  __shared__ int s_insane;
  __shared__ int s_fmt;  // 3=uint8, 2=bf16, 1=4-byte words (int32/fp32)
  const int tid = threadIdx.x;
  if (tid == 0) { s_insane = 0; s_fmt = 1; }
  __syncthreads();

  // --- float dtype probe on queries (even-indexed bf16 halves) ---
  if (tid < 128) {
    unsigned short u = q[2 * tid];
    int e = (u >> 7) & 0xFF;
    if (e < 100 || e > 154) atomicAdd(&s_insane, 1);
  }

  // --- mask format probe: scan nmask BYTES (safe under all hypotheses) ---
  const unsigned int* wi = (const unsigned int*)mraw;
  const int nw = nmask / 4;
  int pri = 0;
  for (int i = tid; i < nw; i += 256) {
    unsigned int w = wi[i];
    if (w == 0u || w == 1u) continue;            // int32-compatible
    if (w == 0x3F803F80u || w == 0x00003F80u) { pri = max(pri, 2); continue; }
    if (w == 0x3F800000u) continue;              // fp32 1.0f (4-byte decode ok)
    unsigned int b0 = w & 0xFFu, b1 = (w >> 8) & 0xFFu,
                 b2 = (w >> 16) & 0xFFu, b3 = (w >> 24) & 0xFFu;
    if (b0 <= 1u && b1 <= 1u && b2 <= 1u && b3 <= 1u) pri = max(pri, 3);
    else pri = max(pri, 2);                      // odd pattern -> bf16 halves
  }
  if (pri) atomicMax(&s_fmt, pri);
  __syncthreads();

  const int fmt = s_fmt;
  for (int i = tid; i < nmask; i += 256) {
    int m;
    if (fmt == 3)      m = ((const unsigned char*)mraw)[i] != 0;
    else if (fmt == 2) m = ((const unsigned short*)mraw)[i] != 0;
    else               m = (wi[i] != 0u);
    mf[i] = (float)m;
  }
  if (tid == 0) flags[0] = (s_insane >= 32) ? 1 : 0;
}

// ---------------------------------------------------------------------------
// Conv1d as tiled GEMM (R2 structure + two safe changes):
//  (a) As padded [16][68]: staging-store bank = (4k+m)%32 -> 2-way (free);
//      R2's [16][64] had 16-way conflicts (SQ_LDS_BANK_CONFLICT = 4.25e7).
//  (b) Register prefetch: each thread owns the SAME 4 A + 4 B elements as
//      R2's strided staging loops (i = tid+256p decomposes identically);
//      next k-tile is loaded into registers during the current kk-compute,
//      hiding global latency behind ~800 cyc of FMA.
// Semantics identical to the R2-passing kernel.
// ---------------------------------------------------------------------------
__global__ __launch_bounds__(256) void k_conv(
    const void* __restrict__ X, const void* __restrict__ W,
    const void* __restrict__ bias, float* __restrict__ Y,
    const int* __restrict__ flags, int xraw,
    int Cin, int Cout, int T, int KW, int pad, int relu) {
  const int inf = flags[0];          // 1 = fp32 inputs
  const int xf = xraw ? inf : 1;
  const int K  = Cin * KW;           // always a multiple of 16 here
  const int b  = blockIdx.z;
  const int m0 = blockIdx.y * 64;
  const int n0 = blockIdx.x * 64;
  const int tid = threadIdx.x;
  const int tx = tid & 15;   // n direction
  const int ty = tid >> 4;   // m direction

  __shared__ float As[16][68];   // [k][m], +4 pad: store bank (4k+m)%32
  __shared__ float Bs[16][65];   // [k][n], +1 pad

  float acc[4][4] = {{0.f}};
  const long xbase = (long)b * Cin * T;

  // Per-thread staging ownership (identical to R2's i = tid+256p loops):
  // A: k_a = tid&15 (const), m_a(p) = (tid>>4) + 16p
  // B: n_b = tid&63 (const), k_b(p) = (tid>>6) + 4p
  const int k_a  = tid & 15;
  const int m_a0 = tid >> 4;
  const int n_b  = tid & 63;
  const int k_b0 = tid >> 6;

  float pa[4], pb[4];

  // --- prefetch first tile (k0 = 0) ---
#pragma unroll
  for (int p = 0; p < 4; ++p) {
    const int gm = m0 + m_a0 + 16 * p;
    const int gk = k_a;
    pa[p] = (gm < Cout && gk < K) ? load_sel(W, (long)gm * K + gk, inf) : 0.f;
  }
#pragma unroll
  for (int p = 0; p < 4; ++p) {
    const int gk = k_b0 + 4 * p;
    float v = 0.f;
    if (gk < K) {
      const int ci = gk / KW;
      const int dk = gk - ci * KW;
      const int t = n0 + n_b + dk - pad;
      if (t >= 0 && t < T) v = load_sel(X, xbase + (long)ci * T + t, xf);
    }
    pb[p] = v;
  }

  for (int k0 = 0; k0 < K; k0 += 16) {
    // --- commit prefetched tile to LDS ---
#pragma unroll
    for (int p = 0; p < 4; ++p) As[k_a][m_a0 + 16 * p] = pa[p];
#pragma unroll
    for (int p = 0; p < 4; ++p) Bs[k_b0 + 4 * p][n_b] = pb[p];
    __syncthreads();

    // --- prefetch next tile into registers (overlaps compute below) ---
    const int kn = k0 + 16;
    if (kn < K) {
#pragma unroll
      for (int p = 0; p < 4; ++p) {
        const int gm = m0 + m_a0 + 16 * p;
        const int gk = kn + k_a;
        pa[p] = (gm < Cout && gk < K) ? load_sel(W, (long)gm * K + gk, inf) : 0.f;
      }
#pragma unroll
      for (int p = 0; p < 4; ++p) {
        const int gk = kn + k_b0 + 4 * p;
        float v = 0.f;
        if (gk < K) {
          const int ci = gk / KW;
          const int dk = gk - ci * KW;
          const int t = n0 + n_b + dk - pad;
          if (t >= 0 && t < T) v = load_sel(X, xbase + (long)ci * T + t, xf);
        }
        pb[p] = v;
      }
    }

    // --- compute on the committed tile ---
#pragma unroll
    for (int kk = 0; kk < 16; ++kk) {
      float a[4], bv[4];
#pragma unroll
      for (int i = 0; i < 4; ++i) a[i] = As[kk][ty * 4 + i];
#pragma unroll
      for (int j = 0; j < 4; ++j) bv[j] = Bs[kk][tx * 4 + j];
#pragma unroll
      for (int i = 0; i < 4; ++i)
#pragma unroll
        for (int j = 0; j < 4; ++j)
          acc[i][j] = fmaf(a[i], bv[j], acc[i][j]);
    }
    __syncthreads();
  }

#pragma unroll
  for (int i = 0; i < 4; ++i) {
    int gm = m0 + ty * 4 + i;
    if (gm >= Cout) continue;
    float bi = load_sel(bias, gm, inf);
#pragma unroll
    for (int j = 0; j < 4; ++j) {
      int gn = n0 + tx * 4 + j;
      if (gn >= T) continue;
      float v = acc[i][j] + bi;
      if (relu) v = fmaxf(v, 0.f);
      Y[((long)b * Cout + gm) * T + gn] = v;
    }
  }
}

// ---------------------------------------------------------------------------
// Distance + log_softmax + prior + masked softmax. R2-exact (proven passing).
// ---------------------------------------------------------------------------
__global__ __launch_bounds__(256) void k_dist(
    const float* __restrict__ qe, const float* __restrict__ ke,
    const void* __restrict__ prior, const float* __restrict__ mf,
    void* __restrict__ out, const int* __restrict__ flags) {
  const int f   = flags[0];
  const int t1  = blockIdx.x;
  const int b   = blockIdx.y;
  const int tid = threadIdx.x;

  __shared__ float qv[CA];
  __shared__ float red[8];

  if (tid < CA) qv[tid] = qe[((long)b * CA + tid) * T1_ + t1];
  __syncthreads();

  const int t2 = tid;
  const bool valid = (t2 < T2_);
  float x = -INFINITY;
  if (valid) {
    const float* kb = ke + (long)b * CA * T2_ + t2;
    float s = 0.f;
#pragma unroll 8
    for (int c = 0; c < CA; ++c) {
      float d = qv[c] - kb[c * T2_];
      s = fmaf(d, d, s);
    }
    x = -0.0005f * s;
  }

  // --- max over row ---
  float m = x;
#pragma unroll
  for (int o = 32; o > 0; o >>= 1) m = fmaxf(m, __shfl_down(m, o, 64));
  if ((tid & 63) == 0) red[tid >> 6] = m;
  __syncthreads();
  const float M1 = fmaxf(fmaxf(red[0], red[1]), fmaxf(red[2], red[3]));

  // --- sum exp ---
  float e = (x == -INFINITY) ? 0.f : expf(x - M1);
  float ssum = e;
#pragma unroll
  for (int o = 32; o > 0; o >>= 1) ssum += __shfl_down(ssum, o, 64);
  if ((tid & 63) == 0) red[(tid >> 6) + 4] = ssum;
  __syncthreads();
  const float S1 = red[4] + red[5] + red[6] + red[7];
  const float logZ = logf(S1);

  const long oidx = ((long)b * T1_ + t1) * T2_ + t2;
  const long N = (long)B_ * T1_ * T2_;
  float lp = -INFINITY;
  if (valid) {
    float pr = load_sel(prior, oidx, f);
    lp = (x - M1 - logZ) + logf(fmaxf(pr, 0.f) + 1e-8f);
    if (f) ((float*)out)[N + oidx] = lp;
    else   ((bf16*)out)[N + oidx] = __float2bfloat16(lp);
  }

  float xm = lp;
  if (valid && mf[b * T2_ + t2] != 0.f) xm = -INFINITY;

  __syncthreads();  // red[0..3] about to be rewritten
  float m2 = xm;
#pragma unroll
  for (int o = 32; o > 0; o >>= 1) m2 = fmaxf(m2, __shfl_down(m2, o, 64));
  if ((tid & 63) == 0) red[tid >> 6] = m2;
  __syncthreads();
  const float M2 = fmaxf(fmaxf(red[0], red[1]), fmaxf(red[2], red[3]));

  float e2 = (xm == -INFINITY) ? 0.f : expf(xm - M2);
  float s2 = e2;
#pragma unroll
  for (int o = 32; o > 0; o >>= 1) s2 += __shfl_down(s2, o, 64);
  if ((tid & 63) == 0) red[(tid >> 6) + 4] = s2;
  __syncthreads();
  const float S2 = red[4] + red[5] + red[6] + red[7];

  if (valid) {
    float a = (S2 > 0.f) ? (e2 / S2) : 0.f;
    if (f) ((float*)out)[oidx] = a;
    else   ((bf16*)out)[oidx] = __float2bfloat16(a);
  }
}

// ---------------------------------------------------------------------------
extern "C" void kernel_launch(void* const* d_in, const int* in_sizes, int n_in,
                              void* d_out, int out_size, void* d_ws, size_t ws_size,
                              hipStream_t stream) {
  const void* queries = d_in[0];
  const void* keys    = d_in[1];
  // d_in[2] = query_lens (unused by reference math)
  const void* mask    = d_in[3];
  const void* prior   = d_in[4];
  const void* kp_w1 = d_in[5];
  const void* kp_b1 = d_in[6];
  const void* kp_w2 = d_in[7];
  const void* kp_b2 = d_in[8];
  const void* qp_w1 = d_in[9];
  const void* qp_b1 = d_in[10];
  const void* qp_w2 = d_in[11];
  const void* qp_b2 = d_in[12];
  const void* qp_w3 = d_in[13];
  const void* qp_b3 = d_in[14];

  // Workspace layout (fp32) — R2-exact.
  float* ws  = (float*)d_ws;
  float* ke1 = ws;                                  // 8*1024*200 = 1,638,400
  float* ke  = ke1 + (long)B_ * 1024 * T2_;         //   128,000
  float* qe1 = ke  + (long)B_ * CA   * T2_;         // 1,024,000
  float* qe2 = qe1 + (long)B_ * 160  * T1_;         //   512,000
  float* qe  = qe2 + (long)B_ * CM   * T1_;         //   512,000
  float* mf  = qe  + (long)B_ * CA   * T1_;         //     1,600
  int* flags = (int*)(mf + B_ * T2_);

  k_detect<<<1, 256, 0, stream>>>((const unsigned short*)queries, mask,
                                  B_ * T2_, mf, flags);

  // key_proj: Conv1d(512->1024, k3, pad1) + ReLU ; Conv1d(1024->80, k1)
  k_conv<<<dim3(4, 16, B_), 256, 0, stream>>>(
      keys, kp_w1, kp_b1, ke1, flags, 1, CT, 1024, T2_, 3, 1, 1);
  k_conv<<<dim3(4, 2, B_), 256, 0, stream>>>(
      ke1, kp_w2, kp_b2, ke, flags, 0, 1024, CA, T2_, 1, 0, 0);

  // query_proj: Conv1d(80->160,k3,pad1)+ReLU; Conv1d(160->80,k1)+ReLU; Conv1d(80->80,k1)
  k_conv<<<dim3(13, 3, B_), 256, 0, stream>>>(
      queries, qp_w1, qp_b1, qe1, flags, 1, CM, 160, T1_, 3, 1, 1);
  k_conv<<<dim3(13, 2, B_), 256, 0, stream>>>(
      qe1, qp_w2, qp_b2, qe2, flags, 0, 160, CM, T1_, 1, 0, 1);
  k_conv<<<dim3(13, 2, B_), 256, 0, stream>>>(
      qe2, qp_w3, qp_b3, qe, flags, 0, CM, CA, T1_, 1, 0, 0);

  k_dist<<<dim3(T1_, B_), 256, 0, stream>>>(qe, ke, prior, mf, d_out, flags);
}

// Round 7
// 233.030 us; speedup vs baseline: 2.9622x; 2.0045x over previous
//
#include <hip/hip_runtime.h>
#include <hip/hip_bf16.h>
#include <math.h>

// Problem dims (fixed by setup_inputs)
#define B_  8
#define CM  80
#define T1_ 800
#define CT  512
#define T2_ 200
#define CA  80

using bf16 = __hip_bfloat16;
typedef __attribute__((ext_vector_type(8))) short bf16x8;
typedef __attribute__((ext_vector_type(4))) float f32x4;

// Runtime-dtype float load: isf32 selects fp32 vs bf16 interpretation.
// Evidence (R1..R6): flags resolves to fp32 on this dataset; kept runtime
// for robustness since it costs nothing.
__device__ __forceinline__ float load_sel(const void* p, long idx, int isf32) {
  if (isf32) return ((const float*)p)[idx];
  return __bfloat162float(((const bf16*)p)[idx]);
}

__device__ __forceinline__ unsigned short f2bf(float x) {
  bf16 h = __float2bfloat16(x);
  return *reinterpret_cast<unsigned short*>(&h);
}

// ---------------------------------------------------------------------------
// Detection + mask normalization (single block). R2/R6-exact (proven).
// ---------------------------------------------------------------------------
__global__ void k_detect(const unsigned short* __restrict__ q,
                         const void* __restrict__ mraw, int nmask,
                         float* __restrict__ mf, int* __restrict__ flags) {
  __shared__ int s_insane;
  __shared__ int s_fmt;
  const int tid = threadIdx.x;
  if (tid == 0) { s_insane = 0; s_fmt = 1; }
  __syncthreads();

  if (tid < 128) {
    unsigned short u = q[2 * tid];
    int e = (u >> 7) & 0xFF;
    if (e < 100 || e > 154) atomicAdd(&s_insane, 1);
  }

  const unsigned int* wi = (const unsigned int*)mraw;
  const int nw = nmask / 4;
  int pri = 0;
  for (int i = tid; i < nw; i += 256) {
    unsigned int w = wi[i];
    if (w == 0u || w == 1u) continue;
    if (w == 0x3F803F80u || w == 0x00003F80u) { pri = max(pri, 2); continue; }
    if (w == 0x3F800000u) continue;
    unsigned int b0 = w & 0xFFu, b1 = (w >> 8) & 0xFFu,
                 b2 = (w >> 16) & 0xFFu, b3 = (w >> 24) & 0xFFu;
    if (b0 <= 1u && b1 <= 1u && b2 <= 1u && b3 <= 1u) pri = max(pri, 3);
    else pri = max(pri, 2);
  }
  if (pri) atomicMax(&s_fmt, pri);
  __syncthreads();

  const int fmt = s_fmt;
  for (int i = tid; i < nmask; i += 256) {
    int m;
    if (fmt == 3)      m = ((const unsigned char*)mraw)[i] != 0;
    else if (fmt == 2) m = ((const unsigned short*)mraw)[i] != 0;
    else               m = (wi[i] != 0u);
    mf[i] = (float)m;
  }
  if (tid == 0) flags[0] = (s_insane >= 32) ? 1 : 0;
}

// ---------------------------------------------------------------------------
// Convert + transpose: (B, C, T) float-per-flags -> (B, T, C) bf16.
// ---------------------------------------------------------------------------
__global__ void k_cvt_t(const void* __restrict__ X, bf16* __restrict__ XT,
                        const int* __restrict__ flags, int C, int T) {
  __shared__ float tile[32][33];
  const int f = flags[0];
  const int b = blockIdx.z;
  const int t0 = blockIdx.x * 32, c0 = blockIdx.y * 32;
  const int tx = threadIdx.x, ty = threadIdx.y;
  if (c0 + ty < C && t0 + tx < T)
    tile[ty][tx] = load_sel(X, ((long)b * C + c0 + ty) * T + t0 + tx, f);
  __syncthreads();
  if (t0 + ty < T && c0 + tx < C)
    XT[((long)b * T + t0 + ty) * C + c0 + tx] = __float2bfloat16(tile[tx][ty]);
}

// ---------------------------------------------------------------------------
// KW=3 weight: (Co, Ci, 3) float-per-flags -> (3, Co, Ci) bf16 (dk-major K).
// ---------------------------------------------------------------------------
__global__ void k_wt3(const void* __restrict__ W, bf16* __restrict__ WT,
                      const int* __restrict__ flags, int Co, int Ci) {
  const int i = blockIdx.x * 256 + threadIdx.x;
  if (i >= Co * Ci) return;
  const int f = flags[0];
  const int co = i / Ci, ci = i - co * Ci;
#pragma unroll
  for (int dk = 0; dk < 3; ++dk)
    WT[((long)dk * Co + co) * Ci + ci] =
        __float2bfloat16(load_sel(W, ((long)co * Ci + ci) * 3 + dk, f));
}

// ---------------------------------------------------------------------------
// Elementwise convert float-per-flags -> bf16 (k=1 weights, already [co][ci]).
// ---------------------------------------------------------------------------
__global__ void k_cvt(const void* __restrict__ W, bf16* __restrict__ O,
                      const int* __restrict__ flags, int n) {
  const int i = blockIdx.x * 256 + threadIdx.x;
  if (i < n) O[i] = __float2bfloat16(load_sel(W, i, flags[0]));
}

// ---------------------------------------------------------------------------
// Conv1d as bf16 MFMA GEMM over flattened N = B*T.
//   C[m][n] = sum_k WT[dk][m][ci] * XT[b][t+dk-pad][ci], k ordered dk-major.
// 256 thr = 4 waves; 64x64 tile; BK=32; waves 2x2 of 32x32; each wave 2x2
// MFMA 16x16x32. LDS [row][k] stride 56 (112 B: 16B-aligned, 28-bank stride
// -> only free 2-way conflicts). Requires Cin%8==0, Cout%16==0, N%64==0.
// outmode: 0 = bf16 [n][Cout]; 1 = fp32 [n][Cout] (== [b][t][c] contiguous).
// ---------------------------------------------------------------------------
#define LDSW 56
__global__ __launch_bounds__(256) void k_conv_mfma(
    const bf16* __restrict__ XT, const bf16* __restrict__ WT,
    const void* __restrict__ bias, void* __restrict__ Y,
    const int* __restrict__ flags,
    int Cin, int Cout, int T, int KW, int pad, int relu, int outmode) {
  const int inf = flags[0];
  const int K = Cin * KW;
  const int m0 = blockIdx.y * 64;
  const int n0 = blockIdx.x * 64;
  const int tid = threadIdx.x;
  const int wave = tid >> 6;
  const int lane = tid & 63;

  __shared__ __align__(16) short As[64 * LDSW];
  __shared__ __align__(16) short Bs[64 * LDSW];

  const int row = tid >> 2;          // 0..63
  const int koff = (tid & 3) * 8;    // 0,8,16,24
  const int n = n0 + row;
  const int bb = n / T;
  const int t = n - bb * T;

  const int wm = (wave >> 1) * 32;
  const int wn = (wave & 1) * 32;
  const int fm = lane & 15;
  const int quad = lane >> 4;

  f32x4 acc[2][2] = {};

  const short* ap0 = As + (wm + fm) * LDSW + quad * 8;
  const short* bp0 = Bs + (wn + fm) * LDSW + quad * 8;

  for (int k0 = 0; k0 < K; k0 += 32) {
    {
      const int k = k0 + koff;
      const int m = m0 + row;
      uint4 v = {0u, 0u, 0u, 0u};
      if (m < Cout && k < K) {
        const int dk = k / Cin;    // Cin%8==0 -> 8-chunk never straddles dk
        const int ci = k - dk * Cin;
        v = *(const uint4*)(WT + ((long)dk * Cout + m) * Cin + ci);
      }
      *(uint4*)(As + row * LDSW + koff) = v;
    }
    {
      const int k = k0 + koff;
      uint4 v = {0u, 0u, 0u, 0u};
      if (k < K) {
        const int dk = k / Cin;
        const int ci = k - dk * Cin;
        const int tt = t + dk - pad;
        if (tt >= 0 && tt < T)
          v = *(const uint4*)(XT + ((long)bb * T + tt) * Cin + ci);
      }
      *(uint4*)(Bs + row * LDSW + koff) = v;
    }
    __syncthreads();
    {
      bf16x8 a0 = *(const bf16x8*)(ap0);
      bf16x8 a1 = *(const bf16x8*)(ap0 + 16 * LDSW);
      bf16x8 b0 = *(const bf16x8*)(bp0);
      bf16x8 b1 = *(const bf16x8*)(bp0 + 16 * LDSW);
      acc[0][0] = __builtin_amdgcn_mfma_f32_16x16x32_bf16(a0, b0, acc[0][0], 0, 0, 0);
      acc[0][1] = __builtin_amdgcn_mfma_f32_16x16x32_bf16(a0, b1, acc[0][1], 0, 0, 0);
      acc[1][0] = __builtin_amdgcn_mfma_f32_16x16x32_bf16(a1, b0, acc[1][0], 0, 0, 0);
      acc[1][1] = __builtin_amdgcn_mfma_f32_16x16x32_bf16(a1, b1, acc[1][1], 0, 0, 0);
    }
    __syncthreads();
  }

  // Epilogue: D col(n) = lane&15, row(m) = quad*4 + reg  [m89-verified].
#pragma unroll
  for (int mi = 0; mi < 2; ++mi) {
    const int mrow = m0 + wm + mi * 16 + quad * 4;
    if (mrow >= Cout) continue;
    float bi[4];
#pragma unroll
    for (int r = 0; r < 4; ++r) bi[r] = load_sel(bias, mrow + r, inf);
#pragma unroll
    for (int ni = 0; ni < 2; ++ni) {
      const int ncol = n0 + wn + ni * 16 + fm;
      const long base = (long)ncol * Cout + mrow;
      float o[4];
#pragma unroll
      for (int r = 0; r < 4; ++r) {
        float v = acc[mi][ni][r] + bi[r];
        if (relu) v = fmaxf(v, 0.f);
        o[r] = v;
      }
      if (outmode == 0) {
        ushort4 u;
        u.x = f2bf(o[0]); u.y = f2bf(o[1]); u.z = f2bf(o[2]); u.w = f2bf(o[3]);
        *(ushort4*)((bf16*)Y + base) = u;
      } else {
        *(float4*)((float*)Y + base) = make_float4(o[0], o[1], o[2], o[3]);
      }
    }
  }
}

// ---------------------------------------------------------------------------
// Distance + log_softmax + prior + masked softmax. One block per (b, t1).
// qeT/keT fp32 in [b][t][c] (c contiguous). Guards proven in R2/R6.
// ---------------------------------------------------------------------------
__global__ __launch_bounds__(256) void k_dist(
    const float* __restrict__ qeT, const float* __restrict__ keT,
    const void* __restrict__ prior, const float* __restrict__ mf,
    void* __restrict__ out, const int* __restrict__ flags) {
  const int f   = flags[0];
  const int t1  = blockIdx.x;
  const int b   = blockIdx.y;
  const int tid = threadIdx.x;

  __shared__ float qv[CA];
  __shared__ float red[8];

  if (tid < CA) qv[tid] = qeT[((long)b * T1_ + t1) * CA + tid];
  __syncthreads();

  const int t2 = tid;
  const bool valid = (t2 < T2_);
  float x = -INFINITY;
  if (valid) {
    const float4* kb = (const float4*)(keT + ((long)b * T2_ + t2) * CA);
    float s = 0.f;
#pragma unroll
    for (int j = 0; j < CA / 4; ++j) {
      float4 kv = kb[j];
      float d;
      d = qv[4 * j + 0] - kv.x; s = fmaf(d, d, s);
      d = qv[4 * j + 1] - kv.y; s = fmaf(d, d, s);
      d = qv[4 * j + 2] - kv.z; s = fmaf(d, d, s);
      d = qv[4 * j + 3] - kv.w; s = fmaf(d, d, s);
    }
    x = -0.0005f * s;
  }

  float m = x;
#pragma unroll
  for (int o = 32; o > 0; o >>= 1) m = fmaxf(m, __shfl_down(m, o, 64));
  if ((tid & 63) == 0) red[tid >> 6] = m;
  __syncthreads();
  const float M1 = fmaxf(fmaxf(red[0], red[1]), fmaxf(red[2], red[3]));

  float e = (x == -INFINITY) ? 0.f : expf(x - M1);
  float ssum = e;
#pragma unroll
  for (int o = 32; o > 0; o >>= 1) ssum += __shfl_down(ssum, o, 64);
  if ((tid & 63) == 0) red[(tid >> 6) + 4] = ssum;
  __syncthreads();
  const float S1 = red[4] + red[5] + red[6] + red[7];
  const float logZ = logf(S1);

  const long oidx = ((long)b * T1_ + t1) * T2_ + t2;
  const long N = (long)B_ * T1_ * T2_;
  float lp = -INFINITY;
  if (valid) {
    float pr = load_sel(prior, oidx, f);
    lp = (x - M1 - logZ) + logf(fmaxf(pr, 0.f) + 1e-8f);
    if (f) ((float*)out)[N + oidx] = lp;
    else   ((bf16*)out)[N + oidx] = __float2bfloat16(lp);
  }

  float xm = lp;
  if (valid && mf[b * T2_ + t2] != 0.f) xm = -INFINITY;

  __syncthreads();
  float m2 = xm;
#pragma unroll
  for (int o = 32; o > 0; o >>= 1) m2 = fmaxf(m2, __shfl_down(m2, o, 64));
  if ((tid & 63) == 0) red[tid >> 6] = m2;
  __syncthreads();
  const float M2 = fmaxf(fmaxf(red[0], red[1]), fmaxf(red[2], red[3]));

  float e2 = (xm == -INFINITY) ? 0.f : expf(xm - M2);
  float s2 = e2;
#pragma unroll
  for (int o = 32; o > 0; o >>= 1) s2 += __shfl_down(s2, o, 64);
  if ((tid & 63) == 0) red[(tid >> 6) + 4] = s2;
  __syncthreads();
  const float S2 = red[4] + red[5] + red[6] + red[7];

  if (valid) {
    float a = (S2 > 0.f) ? (e2 / S2) : 0.f;
    if (f) ((float*)out)[oidx] = a;
    else   ((bf16*)out)[oidx] = __float2bfloat16(a);
  }
}

// ---------------------------------------------------------------------------
extern "C" void kernel_launch(void* const* d_in, const int* in_sizes, int n_in,
                              void* d_out, int out_size, void* d_ws, size_t ws_size,
                              hipStream_t stream) {
  const void* queries = d_in[0];
  const void* keys    = d_in[1];
  // d_in[2] = query_lens (unused by reference math)
  const void* mask    = d_in[3];
  const void* prior   = d_in[4];
  const void* kp_w1 = d_in[5];
  const void* kp_b1 = d_in[6];
  const void* kp_w2 = d_in[7];
  const void* kp_b2 = d_in[8];
  const void* qp_w1 = d_in[9];
  const void* qp_b1 = d_in[10];
  const void* qp_w2 = d_in[11];
  const void* qp_b2 = d_in[12];
  const void* qp_w3 = d_in[13];
  const void* qp_b3 = d_in[14];

  // ---- Workspace (~14.3 MiB total; R2 proved >= 15.26 MB available) ----
  float* keT   = (float*)d_ws;            // 128,000 f  [b][200][80]
  float* qeT   = keT + 128000;            // 512,000 f  [b][800][80]
  float* mf    = qeT + 512000;            //   1,600 f
  int*   flags = (int*)(mf + 1600);       //      16 f
  bf16* keysT    = (bf16*)(flags + 16);   //   819,200  [b][200][512]
  bf16* queriesT = keysT + 819200;        //   512,000  [b][800][80]
  bf16* w1T      = queriesT + 512000;     // 1,572,864  [3][1024][512]
  bf16* qw1T     = w1T + 1572864;         //    38,400  [3][160][80]
  bf16* kw2c     = qw1T + 38400;          //    81,920  [80][1024]
  bf16* qw2c     = kw2c + 81920;          //    12,800  [80][160]
  bf16* qw3c     = qw2c + 12800;          //     6,400  [80][80]
  bf16* ke1T     = qw3c + 6400;           // 1,638,400  [1600][1024]
  bf16* qe1T     = ke1T + 1638400;        // 1,024,000  [6400][160]
  bf16* qe2T     = qe1T + 1024000;        //   512,000  [6400][80]

  k_detect<<<1, 256, 0, stream>>>((const unsigned short*)queries, mask,
                                  B_ * T2_, mf, flags);

  // ---- convert/reorder (flag-driven loads, bf16 out) ----
  k_cvt_t<<<dim3(7, 16, B_), dim3(32, 32), 0, stream>>>(keys, keysT, flags, CT, T2_);
  k_cvt_t<<<dim3(25, 3, B_), dim3(32, 32), 0, stream>>>(queries, queriesT, flags, CM, T1_);
  k_wt3<<<(1024 * 512 + 255) / 256, 256, 0, stream>>>(kp_w1, w1T, flags, 1024, CT);
  k_wt3<<<(160 * 80 + 255) / 256, 256, 0, stream>>>(qp_w1, qw1T, flags, 160, CM);
  k_cvt<<<(80 * 1024 + 255) / 256, 256, 0, stream>>>(kp_w2, kw2c, flags, 80 * 1024);
  k_cvt<<<(80 * 160 + 255) / 256, 256, 0, stream>>>(qp_w2, qw2c, flags, 80 * 160);
  k_cvt<<<(80 * 80 + 255) / 256, 256, 0, stream>>>(qp_w3, qw3c, flags, 80 * 80);

  // ---- key_proj: Conv(512->1024,k3,pad1)+ReLU ; Conv(1024->80,k1) -> fp32 ----
  k_conv_mfma<<<dim3(25, 16), 256, 0, stream>>>(
      keysT, w1T, kp_b1, ke1T, flags, CT, 1024, T2_, 3, 1, 1, 0);
  k_conv_mfma<<<dim3(25, 2), 256, 0, stream>>>(
      ke1T, kw2c, kp_b2, keT, flags, 1024, CA, T2_, 1, 0, 0, 1);

  // ---- query_proj: k3+ReLU ; k1+ReLU ; k1 -> fp32 ----
  k_conv_mfma<<<dim3(100, 3), 256, 0, stream>>>(
      queriesT, qw1T, qp_b1, qe1T, flags, CM, 160, T1_, 3, 1, 1, 0);
  k_conv_mfma<<<dim3(100, 2), 256, 0, stream>>>(
      qe1T, qw2c, qp_b2, qe2T, flags, 160, CM, T1_, 1, 0, 1, 0);
  k_conv_mfma<<<dim3(100, 2), 256, 0, stream>>>(
      qe2T, qw3c, qp_b3, qeT, flags, CM, CA, T1_, 1, 0, 0, 1);

  k_dist<<<dim3(T1_, B_), 256, 0, stream>>>(qeT, keT, prior, mf, d_out, flags);
}

// Round 8
// 216.865 us; speedup vs baseline: 3.1830x; 1.0745x over previous
//
#include <hip/hip_runtime.h>
#include <hip/hip_bf16.h>
#include <math.h>

// Problem dims (fixed by setup_inputs)
#define B_  8
#define CM  80
#define T1_ 800
#define CT  512
#define T2_ 200
#define CA  80

using bf16 = __hip_bfloat16;
typedef __attribute__((ext_vector_type(8))) short bf16x8;
typedef __attribute__((ext_vector_type(4))) float f32x4;

// Runtime-dtype float load: isf32 selects fp32 vs bf16 interpretation.
// Evidence (R1..R7): resolves to fp32 on this dataset; kept for robustness.
__device__ __forceinline__ float load_sel(const void* p, long idx, int isf32) {
  if (isf32) return ((const float*)p)[idx];
  return __bfloat162float(((const bf16*)p)[idx]);
}

__device__ __forceinline__ unsigned short f2bf(float x) {
  bf16 h = __float2bfloat16(x);
  return *reinterpret_cast<unsigned short*>(&h);
}

// Inline dtype probe (replaces the k_detect kernel + flags dependency).
// Wave 0 samples 64 even-indexed uint16 halves of `queries`: bf16-stored
// N(0,1) data has sane exponents; fp32-stored data puts mantissa bits there
// (~78% insane). Threshold 16/64. All 256 threads get the flag via LDS.
__device__ __forceinline__ int detect_f32(const unsigned short* q) {
  __shared__ int s_f;
  const int tid = threadIdx.x;
  if (tid < 64) {
    unsigned short u = q[2 * tid];
    int e = (u >> 7) & 0xFF;
    unsigned long long bal = __ballot(e < 100 || e > 154);
    if (tid == 0) s_f = (__popcll(bal) >= 16) ? 1 : 0;
  }
  __syncthreads();
  return s_f;
}

// ---------------------------------------------------------------------------
// ONE fused prep kernel (was 8 launches): input transposes -> bf16 [b][t][c],
// k3 weight reorders -> bf16 [dk][co][ci], k1 weight converts -> bf16,
// bias converts -> fp32, mask normalize. Tasks partitioned by blockIdx.x.
// ---------------------------------------------------------------------------
__device__ void task_cvt_t(const void* X, bf16* XT, int f, int C, int T,
                           int id2, int tilesT, float* smem, int tid) {
  // tiles: (tilesT x tilesC) per batch; id2 = ((b*tilesC)+ct)*tilesT + tt
  const int per_b = tilesT * ((C + 31) >> 5);
  const int b = id2 / per_b;
  const int r = id2 - b * per_b;
  const int ct = r / tilesT, tt = r - ct * tilesT;
  const int c0 = ct * 32, t0 = tt * 32;
  const int tx = tid & 31, trow = tid >> 5;
#pragma unroll
  for (int p = 0; p < 4; ++p) {
    const int cr = trow + 8 * p;
    if (c0 + cr < C && t0 + tx < T)
      smem[cr * 33 + tx] = load_sel(X, ((long)b * C + c0 + cr) * T + t0 + tx, f);
  }
  __syncthreads();
#pragma unroll
  for (int p = 0; p < 4; ++p) {
    const int tr = trow + 8 * p;
    if (t0 + tr < T && c0 + tx < C)
      XT[((long)b * T + t0 + tr) * C + c0 + tx] =
          __float2bfloat16(smem[tx * 33 + tr]);
  }
}

__device__ void task_wt3(const void* W, bf16* WT, int f, int Co, int Ci,
                         int id2, int tid) {
  const int i = id2 * 256 + tid;
  if (i >= Co * Ci) return;
  const int co = i / Ci, ci = i - co * Ci;
#pragma unroll
  for (int dk = 0; dk < 3; ++dk)
    WT[((long)dk * Co + co) * Ci + ci] =
        __float2bfloat16(load_sel(W, ((long)co * Ci + ci) * 3 + dk, f));
}

__device__ void task_cvt(const void* W, bf16* O, int f, int n, int id2, int tid) {
  const int i = id2 * 256 + tid;
  if (i < n) O[i] = __float2bfloat16(load_sel(W, i, f));
}

__global__ __launch_bounds__(256) void k_prep(
    const void* __restrict__ queries, const void* __restrict__ keys,
    const void* __restrict__ mask,
    const void* __restrict__ kp_w1, const void* __restrict__ kp_b1,
    const void* __restrict__ kp_w2, const void* __restrict__ kp_b2,
    const void* __restrict__ qp_w1, const void* __restrict__ qp_b1,
    const void* __restrict__ qp_w2, const void* __restrict__ qp_b2,
    const void* __restrict__ qp_w3, const void* __restrict__ qp_b3,
    bf16* __restrict__ keysT, bf16* __restrict__ queriesT,
    bf16* __restrict__ w1T, bf16* __restrict__ qw1T,
    bf16* __restrict__ kw2c, bf16* __restrict__ qw2c, bf16* __restrict__ qw3c,
    float* __restrict__ biasf, float* __restrict__ mf) {
  __shared__ float smem[32 * 33];
  const int tid = threadIdx.x;
  const int f = detect_f32((const unsigned short*)queries);
  int id = blockIdx.x;

  // keys transpose: (8,512,200)->(8,200,512); 7 t-tiles x 16 c-tiles x 8 = 896
  if (id < 896) { task_cvt_t(keys, keysT, f, CT, T2_, id, 7, smem, tid); return; }
  id -= 896;
  // queries transpose: (8,80,800)->(8,800,80); 25 x 3 x 8 = 600
  if (id < 600) { task_cvt_t(queries, queriesT, f, CM, T1_, id, 25, smem, tid); return; }
  id -= 600;
  // kp_w1 (1024,512,3) -> (3,1024,512): 524288/256 = 2048
  if (id < 2048) { task_wt3(kp_w1, w1T, f, 1024, CT, id, tid); return; }
  id -= 2048;
  // qp_w1 (160,80,3) -> (3,160,80): 50
  if (id < 50) { task_wt3(qp_w1, qw1T, f, 160, CM, id, tid); return; }
  id -= 50;
  // kp_w2 (80,1024): 320
  if (id < 320) { task_cvt(kp_w2, kw2c, f, 80 * 1024, id, tid); return; }
  id -= 320;
  // qp_w2 (80,160): 50
  if (id < 50) { task_cvt(qp_w2, qw2c, f, 80 * 160, id, tid); return; }
  id -= 50;
  // qp_w3 (80,80): 25
  if (id < 25) { task_cvt(qp_w3, qw3c, f, 80 * 80, id, tid); return; }
  id -= 25;

  if (id == 0) {
    // biases -> fp32 [kb1(1024) kb2(80) qb1(160) qb2(80) qb3(80)]
    for (int i = tid; i < 1424; i += 256) {
      float v;
      if (i < 1024)      v = load_sel(kp_b1, i, f);
      else if (i < 1104) v = load_sel(kp_b2, i - 1024, f);
      else if (i < 1264) v = load_sel(qp_b1, i - 1104, f);
      else if (i < 1344) v = load_sel(qp_b2, i - 1264, f);
      else               v = load_sel(qp_b3, i - 1344, f);
      biasf[i] = v;
    }
    return;
  }

  // mask normalize (R2-proven format detection: uint8 / bf16 / 4-byte words)
  {
    int* s_fmt = (int*)smem;
    const int nmask = B_ * T2_;
    if (tid == 0) s_fmt[0] = 1;
    __syncthreads();
    const unsigned int* wi = (const unsigned int*)mask;
    const int nw = nmask / 4;
    int pri = 0;
    for (int i = tid; i < nw; i += 256) {
      unsigned int w = wi[i];
      if (w == 0u || w == 1u) continue;
      if (w == 0x3F803F80u || w == 0x00003F80u) { pri = max(pri, 2); continue; }
      if (w == 0x3F800000u) continue;
      unsigned int b0 = w & 0xFFu, b1 = (w >> 8) & 0xFFu,
                   b2 = (w >> 16) & 0xFFu, b3 = (w >> 24) & 0xFFu;
      if (b0 <= 1u && b1 <= 1u && b2 <= 1u && b3 <= 1u) pri = max(pri, 3);
      else pri = max(pri, 2);
    }
    if (pri) atomicMax(&s_fmt[0], pri);
    __syncthreads();
    const int fmt = s_fmt[0];
    for (int i = tid; i < nmask; i += 256) {
      int m;
      if (fmt == 3)      m = ((const unsigned char*)mask)[i] != 0;
      else if (fmt == 2) m = ((const unsigned short*)mask)[i] != 0;
      else               m = (wi[i] != 0u);
      mf[i] = (float)m;
    }
  }
}

// ---------------------------------------------------------------------------
// Conv1d as bf16 MFMA GEMM over flattened N = B*T (R7-proven math; bias is
// now a plain fp32 array; flags dependency removed).
// outmode: 0 = bf16 [n][Cout]; 1 = fp32 [n][Cout] (== [b][t][c] contiguous).
// ---------------------------------------------------------------------------
#define LDSW 56
__global__ __launch_bounds__(256) void k_conv_mfma(
    const bf16* __restrict__ XT, const bf16* __restrict__ WT,
    const float* __restrict__ bias, void* __restrict__ Y,
    int Cin, int Cout, int T, int KW, int pad, int relu, int outmode) {
  const int K = Cin * KW;
  const int m0 = blockIdx.y * 64;
  const int n0 = blockIdx.x * 64;
  const int tid = threadIdx.x;
  const int wave = tid >> 6;
  const int lane = tid & 63;

  __shared__ __align__(16) short As[64 * LDSW];
  __shared__ __align__(16) short Bs[64 * LDSW];

  const int row = tid >> 2;          // 0..63
  const int koff = (tid & 3) * 8;    // 0,8,16,24
  const int n = n0 + row;
  const int bb = n / T;
  const int t = n - bb * T;

  const int wm = (wave >> 1) * 32;
  const int wn = (wave & 1) * 32;
  const int fm = lane & 15;
  const int quad = lane >> 4;

  f32x4 acc[2][2] = {};

  const short* ap0 = As + (wm + fm) * LDSW + quad * 8;
  const short* bp0 = Bs + (wn + fm) * LDSW + quad * 8;

  for (int k0 = 0; k0 < K; k0 += 32) {
    {
      const int k = k0 + koff;
      const int m = m0 + row;
      uint4 v = {0u, 0u, 0u, 0u};
      if (m < Cout && k < K) {
        const int dk = k / Cin;    // Cin%8==0 -> 8-chunk never straddles dk
        const int ci = k - dk * Cin;
        v = *(const uint4*)(WT + ((long)dk * Cout + m) * Cin + ci);
      }
      *(uint4*)(As + row * LDSW + koff) = v;
    }
    {
      const int k = k0 + koff;
      uint4 v = {0u, 0u, 0u, 0u};
      if (k < K) {
        const int dk = k / Cin;
        const int ci = k - dk * Cin;
        const int tt = t + dk - pad;
        if (tt >= 0 && tt < T)
          v = *(const uint4*)(XT + ((long)bb * T + tt) * Cin + ci);
      }
      *(uint4*)(Bs + row * LDSW + koff) = v;
    }
    __syncthreads();
    {
      bf16x8 a0 = *(const bf16x8*)(ap0);
      bf16x8 a1 = *(const bf16x8*)(ap0 + 16 * LDSW);
      bf16x8 b0 = *(const bf16x8*)(bp0);
      bf16x8 b1 = *(const bf16x8*)(bp0 + 16 * LDSW);
      acc[0][0] = __builtin_amdgcn_mfma_f32_16x16x32_bf16(a0, b0, acc[0][0], 0, 0, 0);
      acc[0][1] = __builtin_amdgcn_mfma_f32_16x16x32_bf16(a0, b1, acc[0][1], 0, 0, 0);
      acc[1][0] = __builtin_amdgcn_mfma_f32_16x16x32_bf16(a1, b0, acc[1][0], 0, 0, 0);
      acc[1][1] = __builtin_amdgcn_mfma_f32_16x16x32_bf16(a1, b1, acc[1][1], 0, 0, 0);
    }
    __syncthreads();
  }

  // Epilogue: D col(n) = lane&15, row(m) = quad*4 + reg  [m89-verified].
#pragma unroll
  for (int mi = 0; mi < 2; ++mi) {
    const int mrow = m0 + wm + mi * 16 + quad * 4;
    if (mrow >= Cout) continue;
    float bi[4];
#pragma unroll
    for (int r = 0; r < 4; ++r) bi[r] = bias[mrow + r];
#pragma unroll
    for (int ni = 0; ni < 2; ++ni) {
      const int ncol = n0 + wn + ni * 16 + fm;
      const long base = (long)ncol * Cout + mrow;
      float o[4];
#pragma unroll
      for (int r = 0; r < 4; ++r) {
        float v = acc[mi][ni][r] + bi[r];
        if (relu) v = fmaxf(v, 0.f);
        o[r] = v;
      }
      if (outmode == 0) {
        ushort4 u;
        u.x = f2bf(o[0]); u.y = f2bf(o[1]); u.z = f2bf(o[2]); u.w = f2bf(o[3]);
        *(ushort4*)((bf16*)Y + base) = u;
      } else {
        *(float4*)((float*)Y + base) = make_float4(o[0], o[1], o[2], o[3]);
      }
    }
  }
}

// ---------------------------------------------------------------------------
// Distance + log_softmax + prior + masked softmax. One block per (b, t1).
// qeT/keT fp32 in [b][t][c]. R7-proven; flags replaced by inline detect.
// ---------------------------------------------------------------------------
__global__ __launch_bounds__(256) void k_dist(
    const float* __restrict__ qeT, const float* __restrict__ keT,
    const void* __restrict__ prior, const float* __restrict__ mf,
    void* __restrict__ out, const unsigned short* __restrict__ qprobe) {
  const int f = detect_f32(qprobe);
  const int t1  = blockIdx.x;
  const int b   = blockIdx.y;
  const int tid = threadIdx.x;

  __shared__ float qv[CA];
  __shared__ float red[8];

  if (tid < CA) qv[tid] = qeT[((long)b * T1_ + t1) * CA + tid];
  __syncthreads();

  const int t2 = tid;
  const bool valid = (t2 < T2_);
  float x = -INFINITY;
  if (valid) {
    const float4* kb = (const float4*)(keT + ((long)b * T2_ + t2) * CA);
    float s = 0.f;
#pragma unroll
    for (int j = 0; j < CA / 4; ++j) {
      float4 kv = kb[j];
      float d;
      d = qv[4 * j + 0] - kv.x; s = fmaf(d, d, s);
      d = qv[4 * j + 1] - kv.y; s = fmaf(d, d, s);
      d = qv[4 * j + 2] - kv.z; s = fmaf(d, d, s);
      d = qv[4 * j + 3] - kv.w; s = fmaf(d, d, s);
    }
    x = -0.0005f * s;
  }

  float m = x;
#pragma unroll
  for (int o = 32; o > 0; o >>= 1) m = fmaxf(m, __shfl_down(m, o, 64));
  if ((tid & 63) == 0) red[tid >> 6] = m;
  __syncthreads();
  const float M1 = fmaxf(fmaxf(red[0], red[1]), fmaxf(red[2], red[3]));

  float e = (x == -INFINITY) ? 0.f : expf(x - M1);
  float ssum = e;
#pragma unroll
  for (int o = 32; o > 0; o >>= 1) ssum += __shfl_down(ssum, o, 64);
  if ((tid & 63) == 0) red[(tid >> 6) + 4] = ssum;
  __syncthreads();
  const float S1 = red[4] + red[5] + red[6] + red[7];
  const float logZ = logf(S1);

  const long oidx = ((long)b * T1_ + t1) * T2_ + t2;
  const long N = (long)B_ * T1_ * T2_;
  float lp = -INFINITY;
  if (valid) {
    float pr = load_sel(prior, oidx, f);
    lp = (x - M1 - logZ) + logf(fmaxf(pr, 0.f) + 1e-8f);
    if (f) ((float*)out)[N + oidx] = lp;
    else   ((bf16*)out)[N + oidx] = __float2bfloat16(lp);
  }

  float xm = lp;
  if (valid && mf[b * T2_ + t2] != 0.f) xm = -INFINITY;

  __syncthreads();
  float m2 = xm;
#pragma unroll
  for (int o = 32; o > 0; o >>= 1) m2 = fmaxf(m2, __shfl_down(m2, o, 64));
  if ((tid & 63) == 0) red[tid >> 6] = m2;
  __syncthreads();
  const float M2 = fmaxf(fmaxf(red[0], red[1]), fmaxf(red[2], red[3]));

  float e2 = (xm == -INFINITY) ? 0.f : expf(xm - M2);
  float s2 = e2;
#pragma unroll
  for (int o = 32; o > 0; o >>= 1) s2 += __shfl_down(s2, o, 64);
  if ((tid & 63) == 0) red[(tid >> 6) + 4] = s2;
  __syncthreads();
  const float S2 = red[4] + red[5] + red[6] + red[7];

  if (valid) {
    float a = (S2 > 0.f) ? (e2 / S2) : 0.f;
    if (f) ((float*)out)[oidx] = a;
    else   ((bf16*)out)[oidx] = __float2bfloat16(a);
  }
}

// ---------------------------------------------------------------------------
extern "C" void kernel_launch(void* const* d_in, const int* in_sizes, int n_in,
                              void* d_out, int out_size, void* d_ws, size_t ws_size,
                              hipStream_t stream) {
  const void* queries = d_in[0];
  const void* keys    = d_in[1];
  // d_in[2] = query_lens (unused by reference math)
  const void* mask    = d_in[3];
  const void* prior   = d_in[4];
  const void* kp_w1 = d_in[5];
  const void* kp_b1 = d_in[6];
  const void* kp_w2 = d_in[7];
  const void* kp_b2 = d_in[8];
  const void* qp_w1 = d_in[9];
  const void* qp_b1 = d_in[10];
  const void* qp_w2 = d_in[11];
  const void* qp_b2 = d_in[12];
  const void* qp_w3 = d_in[13];
  const void* qp_b3 = d_in[14];

  // ---- Workspace (~14.3 MiB; proven available) ----
  float* keT   = (float*)d_ws;            // 128,000 f  [b][200][80]
  float* qeT   = keT + 128000;            // 512,000 f  [b][800][80]
  float* mf    = qeT + 512000;            //   1,600 f
  float* biasf = mf + 1600;               //   1,424 f (+pad to 1,440)
  bf16* keysT    = (bf16*)(biasf + 1440); //   819,200  [b][200][512]
  bf16* queriesT = keysT + 819200;        //   512,000  [b][800][80]
  bf16* w1T      = queriesT + 512000;     // 1,572,864  [3][1024][512]
  bf16* qw1T     = w1T + 1572864;         //    38,400  [3][160][80]
  bf16* kw2c     = qw1T + 38400;          //    81,920  [80][1024]
  bf16* qw2c     = kw2c + 81920;          //    12,800  [80][160]
  bf16* qw3c     = qw2c + 12800;          //     6,400  [80][80]
  bf16* ke1T     = qw3c + 6400;           // 1,638,400  [1600][1024]
  bf16* qe1T     = ke1T + 1638400;        // 1,024,000  [6400][160]
  bf16* qe2T     = qe1T + 1024000;        //   512,000  [6400][80]

  float* b_k1 = biasf;          // 1024
  float* b_k2 = biasf + 1024;   // 80
  float* b_q1 = biasf + 1104;   // 160
  float* b_q2 = biasf + 1264;   // 80
  float* b_q3 = biasf + 1344;   // 80

  // ---- single fused prep (896+600+2048+50+320+50+25+1+1 = 3991 blocks) ----
  k_prep<<<3991, 256, 0, stream>>>(
      queries, keys, mask,
      kp_w1, kp_b1, kp_w2, kp_b2,
      qp_w1, qp_b1, qp_w2, qp_b2, qp_w3, qp_b3,
      keysT, queriesT, w1T, qw1T, kw2c, qw2c, qw3c, biasf, mf);

  // ---- key_proj: Conv(512->1024,k3,pad1)+ReLU ; Conv(1024->80,k1) -> fp32 ----
  k_conv_mfma<<<dim3(25, 16), 256, 0, stream>>>(
      keysT, w1T, b_k1, ke1T, CT, 1024, T2_, 3, 1, 1, 0);
  k_conv_mfma<<<dim3(25, 2), 256, 0, stream>>>(
      ke1T, kw2c, b_k2, keT, 1024, CA, T2_, 1, 0, 0, 1);

  // ---- query_proj: k3+ReLU ; k1+ReLU ; k1 -> fp32 ----
  k_conv_mfma<<<dim3(100, 3), 256, 0, stream>>>(
      queriesT, qw1T, b_q1, qe1T, CM, 160, T1_, 3, 1, 1, 0);
  k_conv_mfma<<<dim3(100, 2), 256, 0, stream>>>(
      qe1T, qw2c, b_q2, qe2T, 160, CM, T1_, 1, 0, 1, 0);
  k_conv_mfma<<<dim3(100, 2), 256, 0, stream>>>(
      qe2T, qw3c, b_q3, qeT, CM, CA, T1_, 1, 0, 0, 1);

  k_dist<<<dim3(T1_, B_), 256, 0, stream>>>(
      qeT, keT, prior, mf, d_out, (const unsigned short*)queries);
}